// Round 7
// baseline (377.302 us; speedup 1.0000x reference)
//
#include <hip/hip_runtime.h>
#include <cstdint>
#include <cstddef>

#define NEG_SLOPE 0.2f

// Edge packing relies on N <= 65536 (here N = 50000): edge = src | (dst<<16).
#define NB 512        // nodes per bucket
#define LOG_NB 9
#define MAXK 512

__device__ inline unsigned short f2bf(float f) {          // RNE fp32->bf16
    unsigned int u = __float_as_uint(f);
    u += 0x7FFFu + ((u >> 16) & 1u);
    return (unsigned short)(u >> 16);
}
__device__ inline float bf_lo(unsigned int u) { return __uint_as_float(u << 16); }
__device__ inline float bf_hi(unsigned int u) { return __uint_as_float(u & 0xFFFF0000u); }

// ---------------- P1: per-block bucket histogram ----------------
__global__ __launch_bounds__(256) void sort_count_kernel(const int* __restrict__ ei, int E, int EE,
                                                         int K, int CH, int* __restrict__ bcnt) {
    __shared__ int hist[MAXK];
    int tid = threadIdx.x;
    for (int i = tid; i < K; i += 256) hist[i] = 0;
    __syncthreads();
    int lo = blockIdx.x * CH;
    int hi = lo + CH; if (hi > EE) hi = EE;
    for (int e = lo + tid; e < hi; e += 256) {
        int d = (e < E) ? ei[(size_t)E + e] : (e - E);
        atomicAdd(&hist[d >> LOG_NB], 1);
    }
    __syncthreads();
    for (int i = tid; i < K; i += 256)
        if (hist[i]) atomicAdd(&bcnt[i], hist[i]);
}

// ---------------- P2: scan bucket counts ----------------
__global__ void sort_scan_kernel(const int* __restrict__ bcnt, int* __restrict__ boff,
                                 int* __restrict__ bcur, int K, int EE) {
    __shared__ int buf[MAXK];
    int tid = threadIdx.x;   // 512 threads
    int v = (tid < K) ? bcnt[tid] : 0;
    buf[tid] = v;
    __syncthreads();
    for (int o = 1; o < MAXK; o <<= 1) {
        int t = (tid >= o) ? buf[tid - o] : 0;
        __syncthreads();
        buf[tid] += t;
        __syncthreads();
    }
    if (tid < K) {
        int ex = buf[tid] - v;
        boff[tid] = ex;
        bcur[tid] = ex;
    }
    if (tid == K) boff[K] = EE;
}

// ---------------- P3: scatter packed edges into buckets ----------------
__global__ __launch_bounds__(256) void sort_scatter_kernel(const int* __restrict__ ei, int E, int EE,
                                                           int K, int CH, int* __restrict__ bcur,
                                                           unsigned int* __restrict__ bkt) {
    __shared__ int hist[MAXK];
    __shared__ int base[MAXK];
    int tid = threadIdx.x;
    for (int i = tid; i < K; i += 256) hist[i] = 0;
    __syncthreads();
    int lo = blockIdx.x * CH;
    int hi = lo + CH; if (hi > EE) hi = EE;
    for (int e = lo + tid; e < hi; e += 256) {
        int d = (e < E) ? ei[(size_t)E + e] : (e - E);
        atomicAdd(&hist[d >> LOG_NB], 1);
    }
    __syncthreads();
    for (int i = tid; i < K; i += 256) {
        int c = hist[i];
        base[i] = c ? atomicAdd(&bcur[i], c) : 0;
    }
    __syncthreads();
    for (int i = tid; i < K; i += 256) hist[i] = 0;
    __syncthreads();
    for (int e = lo + tid; e < hi; e += 256) {
        int s, d;
        if (e < E) { s = ei[e]; d = ei[(size_t)E + e]; }
        else       { s = e - E; d = e - E; }
        int k = d >> LOG_NB;
        int r = atomicAdd(&hist[k], 1);
        bkt[(size_t)base[k] + r] = (unsigned int)s | ((unsigned int)d << 16);
    }
}

// ---------------- P4: per-bucket CSR finalize ----------------
__global__ __launch_bounds__(256) void sort_finalize_kernel(const unsigned int* __restrict__ bkt,
                                                            const int* __restrict__ boff,
                                                            int* __restrict__ off,
                                                            int* __restrict__ csrc, int N) {
    __shared__ int nhist[NB];
    __shared__ int loff[NB + 1];
    int k = blockIdx.x;
    int tid = threadIdx.x;
    int node0 = k << LOG_NB;
    int nh = N - node0; if (nh > NB) nh = NB;
    int beg = boff[k], end = boff[k + 1];
    for (int i = tid; i < NB; i += 256) nhist[i] = 0;
    __syncthreads();
    for (int e = beg + tid; e < end; e += 256)
        atomicAdd(&nhist[(bkt[e] >> 16) - node0], 1);
    __syncthreads();
    if (tid == 0) {
        int run = beg;
        for (int i = 0; i < nh; i++) { loff[i] = run; run += nhist[i]; }
        loff[nh] = run;
    }
    __syncthreads();
    for (int i = tid; i < nh; i += 256) off[node0 + i] = loff[i];
    if (node0 + nh == N && tid == 0) off[N] = loff[nh];
    for (int i = tid; i < nh; i += 256) nhist[i] = loff[i];
    __syncthreads();
    for (int e = beg + tid; e < end; e += 256) {
        unsigned int p = bkt[e];
        int pos = atomicAdd(&nhist[(p >> 16) - node0], 1);
        csrc[pos] = (int)(p & 0xFFFFu);
    }
}

// ---- GEMM + fused att dots, register-tiled 8 rows x 4 cols per thread ----
// Tile: ROWS x FOUT (ROWS = 8192/FOUT). K staged in halves of 64.

template <int FOUT, int H>
__global__ __launch_bounds__(256) void gemm_att_kernel(const float* __restrict__ X,
                                                       const float* __restrict__ W,
                                                       const float* __restrict__ attS,
                                                       const float* __restrict__ attD,
                                                       unsigned short* __restrict__ Ybf,
                                                       float* __restrict__ as_,
                                                       float* __restrict__ ad_, int N) {
    constexpr int ROWS = 8192 / FOUT;   // 64 (F=128) or 128 (F=64)
    constexpr int CG   = FOUT / 4;
    __shared__ float sX[ROWS][68];      // padded, 16B-aligned float4 over k
    __shared__ float sW[64 * FOUT];
    int tid = threadIdx.x;
    int rowbase = blockIdx.x * ROWS;
    int cg = tid % CG;
    int rg = tid / CG;
    int r0 = rg * 8;

    float acc[8][4];
#pragma unroll
    for (int i = 0; i < 8; i++)
#pragma unroll
        for (int c = 0; c < 4; c++) acc[i][c] = 0.f;

    for (int k0 = 0; k0 < 128; k0 += 64) {
        __syncthreads();
        for (int idx = tid; idx < ROWS * 64; idx += 256) {
            int r = idx >> 6, kk = idx & 63;
            int row = rowbase + r;
            sX[r][kk] = (row < N) ? X[(size_t)row * 128 + k0 + kk] : 0.f;
        }
        for (int idx = tid; idx < 64 * FOUT; idx += 256)
            sW[idx] = W[(size_t)k0 * FOUT + idx];
        __syncthreads();
        for (int k = 0; k < 64; k += 4) {
            float4 xr[8];
#pragma unroll
            for (int i = 0; i < 8; i++)
                xr[i] = *(const float4*)&sX[r0 + i][k];
#pragma unroll
            for (int kk = 0; kk < 4; kk++) {
                float4 wv = ((const float4*)(sW + (size_t)(k + kk) * FOUT))[cg];
#pragma unroll
                for (int i = 0; i < 8; i++) {
                    float xv = (&xr[i].x)[kk];
                    acc[i][0] = fmaf(xv, wv.x, acc[i][0]);
                    acc[i][1] = fmaf(xv, wv.y, acc[i][1]);
                    acc[i][2] = fmaf(xv, wv.z, acc[i][2]);
                    acc[i][3] = fmaf(xv, wv.w, acc[i][3]);
                }
            }
        }
    }

    // store bf16 Y
#pragma unroll
    for (int i = 0; i < 8; i++) {
        int row = rowbase + r0 + i;
        if (row < N) {
            ushort4 v;
            v.x = f2bf(acc[i][0]); v.y = f2bf(acc[i][1]);
            v.z = f2bf(acc[i][2]); v.w = f2bf(acc[i][3]);
            *(ushort4*)(Ybf + (size_t)row * FOUT + cg * 4) = v;
        }
    }

    // fused att dots: reduce each row's 64-channel dot across the head's 16 cg-threads
    float4 asv = ((const float4*)attS)[cg];
    float4 adv = ((const float4*)attD)[cg];
    int head = (H == 2) ? (cg >> 4) : 0;
#pragma unroll
    for (int i = 0; i < 8; i++) {
        float ps = acc[i][0] * asv.x + acc[i][1] * asv.y + acc[i][2] * asv.z + acc[i][3] * asv.w;
        float pd = acc[i][0] * adv.x + acc[i][1] * adv.y + acc[i][2] * adv.z + acc[i][3] * adv.w;
#pragma unroll
        for (int o = 1; o <= 8; o <<= 1) { ps += __shfl_xor(ps, o); pd += __shfl_xor(pd, o); }
        int row = rowbase + r0 + i;
        if ((tid & 15) == 0 && row < N) {
            as_[(size_t)row * H + head] = ps;
            ad_[(size_t)row * H + head] = pd;
        }
    }
}

// ---------------- layer-1 softmax+aggregate: one wave per NODE, both heads ----------------
// lane = (sub = lane>>4 in [0,4), cl = lane&15). Row = 256B = 16 x uint4; cl covers 8 ch.

__global__ __launch_bounds__(256) void agg1_kernel(const unsigned short* __restrict__ xl,
                                                   const float* __restrict__ as_,
                                                   const float* __restrict__ ad_,
                                                   const float* __restrict__ bias,
                                                   const int* __restrict__ off,
                                                   const int* __restrict__ csrc,
                                                   float* __restrict__ out, int N) {
    __shared__ float4 sps[4][64];   // {p0, p1, as_int(src), -}
    int wiw  = threadIdx.x >> 6;
    int lane = threadIdx.x & 63;
    int node = blockIdx.x * 4 + wiw;
    if (node >= N) return;
    int beg = off[node], end = off[node + 1];
    int deg = end - beg;
    float2 adn = ((const float2*)ad_)[node];

    int cl  = lane & 15;
    int sub = lane >> 4;
    int hd1 = (cl >> 3) & 1;    // lanes 8-15 of each 16-group: head 1
    float acc[8];
#pragma unroll
    for (int i = 0; i < 8; i++) acc[i] = 0.f;
    const uint4* xq = (const uint4*)xl + cl;   // + src*16

    if (deg <= 64) {
        int s = 0;
        float t0 = -1e30f, t1 = -1e30f;
        if (lane < deg) {
            s = csrc[beg + lane];
            float2 asv = ((const float2*)as_)[s];
            t0 = asv.x + adn.x; t0 = t0 > 0.f ? t0 : NEG_SLOPE * t0;
            t1 = asv.y + adn.y; t1 = t1 > 0.f ? t1 : NEG_SLOPE * t1;
        }
        float m0 = t0, m1 = t1;
#pragma unroll
        for (int o = 32; o; o >>= 1) {
            m0 = fmaxf(m0, __shfl_xor(m0, o));
            m1 = fmaxf(m1, __shfl_xor(m1, o));
        }
        float e0 = (lane < deg) ? __expf(t0 - m0) : 0.f;
        float e1 = (lane < deg) ? __expf(t1 - m1) : 0.f;
        float s0 = e0, s1 = e1;
#pragma unroll
        for (int o = 32; o; o >>= 1) { s0 += __shfl_xor(s0, o); s1 += __shfl_xor(s1, o); }
        sps[wiw][lane] = make_float4(e0 / s0, e1 / s1, __int_as_float(s), 0.f);
        int iters = (deg + 3) >> 2;
#pragma unroll 8
        for (int j = 0; j < iters; j++) {
            float4 q = sps[wiw][j * 4 + sub];
            float a  = hd1 ? q.y : q.x;
            int   sj = __float_as_int(q.z);
            uint4 v  = xq[(size_t)sj * 16];
            acc[0] = fmaf(a, bf_lo(v.x), acc[0]); acc[1] = fmaf(a, bf_hi(v.x), acc[1]);
            acc[2] = fmaf(a, bf_lo(v.y), acc[2]); acc[3] = fmaf(a, bf_hi(v.y), acc[3]);
            acc[4] = fmaf(a, bf_lo(v.z), acc[4]); acc[5] = fmaf(a, bf_hi(v.z), acc[5]);
            acc[6] = fmaf(a, bf_lo(v.w), acc[6]); acc[7] = fmaf(a, bf_hi(v.w), acc[7]);
        }
    } else {
        // 3-pass fallback
        float m0 = -1e30f, m1 = -1e30f;
        for (int b = beg; b < end; b += 64) {
            int e = b + lane;
            if (e < end) {
                int s = csrc[e];
                float2 asv = ((const float2*)as_)[s];
                float t0 = asv.x + adn.x; t0 = t0 > 0.f ? t0 : NEG_SLOPE * t0;
                float t1 = asv.y + adn.y; t1 = t1 > 0.f ? t1 : NEG_SLOPE * t1;
                m0 = fmaxf(m0, t0); m1 = fmaxf(m1, t1);
            }
        }
#pragma unroll
        for (int o = 32; o; o >>= 1) {
            m0 = fmaxf(m0, __shfl_xor(m0, o));
            m1 = fmaxf(m1, __shfl_xor(m1, o));
        }
        float s0 = 0.f, s1 = 0.f;
        for (int b = beg; b < end; b += 64) {
            int e = b + lane;
            if (e < end) {
                int s = csrc[e];
                float2 asv = ((const float2*)as_)[s];
                float t0 = asv.x + adn.x; t0 = t0 > 0.f ? t0 : NEG_SLOPE * t0;
                float t1 = asv.y + adn.y; t1 = t1 > 0.f ? t1 : NEG_SLOPE * t1;
                s0 += __expf(t0 - m0); s1 += __expf(t1 - m1);
            }
        }
#pragma unroll
        for (int o = 32; o; o >>= 1) { s0 += __shfl_xor(s0, o); s1 += __shfl_xor(s1, o); }
        float i0 = 1.f / s0, i1 = 1.f / s1;
        for (int b = beg; b < end; b += 64) {
            int cnt = end - b; if (cnt > 64) cnt = 64;
            float p0 = 0.f, p1 = 0.f; int s = 0;
            if (lane < cnt) {
                s = csrc[b + lane];
                float2 asv = ((const float2*)as_)[s];
                float t0 = asv.x + adn.x; t0 = t0 > 0.f ? t0 : NEG_SLOPE * t0;
                float t1 = asv.y + adn.y; t1 = t1 > 0.f ? t1 : NEG_SLOPE * t1;
                p0 = __expf(t0 - m0) * i0; p1 = __expf(t1 - m1) * i1;
            }
            sps[wiw][lane] = make_float4(p0, p1, __int_as_float(s), 0.f);
            int iters = (cnt + 3) >> 2;
#pragma unroll 8
            for (int j = 0; j < iters; j++) {
                float4 q = sps[wiw][j * 4 + sub];
                float a  = hd1 ? q.y : q.x;
                int   sj = __float_as_int(q.z);
                uint4 v  = xq[(size_t)sj * 16];
                acc[0] = fmaf(a, bf_lo(v.x), acc[0]); acc[1] = fmaf(a, bf_hi(v.x), acc[1]);
                acc[2] = fmaf(a, bf_lo(v.y), acc[2]); acc[3] = fmaf(a, bf_hi(v.y), acc[3]);
                acc[4] = fmaf(a, bf_lo(v.z), acc[4]); acc[5] = fmaf(a, bf_hi(v.z), acc[5]);
                acc[6] = fmaf(a, bf_lo(v.w), acc[6]); acc[7] = fmaf(a, bf_hi(v.w), acc[7]);
            }
        }
    }
    // reduce over sub (lane bits 4,5)
#pragma unroll
    for (int o = 16; o <= 32; o <<= 1)
#pragma unroll
        for (int i = 0; i < 8; i++) acc[i] += __shfl_xor(acc[i], o);
    if (sub == 0) {
        float* op = out + (size_t)node * 128 + cl * 8;
        const float* bp = bias + cl * 8;
#pragma unroll
        for (int i = 0; i < 8; i++) op[i] = fmaxf(acc[i] + bp[i], 0.f);
    }
}

// ---------------- layer-2 softmax+aggregate: one wave per node, H=1 ----------------
// lane = (sub = lane>>3 in [0,8), cl = lane&7). Row = 128B = 8 x uint4.

__global__ __launch_bounds__(256) void agg2_kernel(const unsigned short* __restrict__ xl,
                                                   const float* __restrict__ as_,
                                                   const float* __restrict__ ad_,
                                                   const float* __restrict__ bias,
                                                   const int* __restrict__ off,
                                                   const int* __restrict__ csrc,
                                                   float* __restrict__ out, int N) {
    __shared__ float2 sps[4][64];   // {p, as_int(src)}
    int wiw  = threadIdx.x >> 6;
    int lane = threadIdx.x & 63;
    int node = blockIdx.x * 4 + wiw;
    if (node >= N) return;
    int beg = off[node], end = off[node + 1];
    int deg = end - beg;
    float adn = ad_[node];

    int cl  = lane & 7;
    int sub = lane >> 3;
    float acc[8];
#pragma unroll
    for (int i = 0; i < 8; i++) acc[i] = 0.f;
    const uint4* xq = (const uint4*)xl + cl;   // + src*8

    if (deg <= 64) {
        int s = 0;
        float t = -1e30f;
        if (lane < deg) {
            s = csrc[beg + lane];
            t = as_[s] + adn;
            t = t > 0.f ? t : NEG_SLOPE * t;
        }
        float m = t;
#pragma unroll
        for (int o = 32; o; o >>= 1) m = fmaxf(m, __shfl_xor(m, o));
        float ev = (lane < deg) ? __expf(t - m) : 0.f;
        float sum = ev;
#pragma unroll
        for (int o = 32; o; o >>= 1) sum += __shfl_xor(sum, o);
        sps[wiw][lane] = make_float2(ev / sum, __int_as_float(s));
        int iters = (deg + 7) >> 3;
#pragma unroll 8
        for (int j = 0; j < iters; j++) {
            float2 q = sps[wiw][j * 8 + sub];
            float a  = q.x;
            int   sj = __float_as_int(q.y);
            uint4 v  = xq[(size_t)sj * 8];
            acc[0] = fmaf(a, bf_lo(v.x), acc[0]); acc[1] = fmaf(a, bf_hi(v.x), acc[1]);
            acc[2] = fmaf(a, bf_lo(v.y), acc[2]); acc[3] = fmaf(a, bf_hi(v.y), acc[3]);
            acc[4] = fmaf(a, bf_lo(v.z), acc[4]); acc[5] = fmaf(a, bf_hi(v.z), acc[5]);
            acc[6] = fmaf(a, bf_lo(v.w), acc[6]); acc[7] = fmaf(a, bf_hi(v.w), acc[7]);
        }
    } else {
        float m = -1e30f;
        for (int b = beg; b < end; b += 64) {
            int e = b + lane;
            if (e < end) {
                float t = as_[csrc[e]] + adn;
                t = t > 0.f ? t : NEG_SLOPE * t;
                m = fmaxf(m, t);
            }
        }
#pragma unroll
        for (int o = 32; o; o >>= 1) m = fmaxf(m, __shfl_xor(m, o));
        float sum = 0.f;
        for (int b = beg; b < end; b += 64) {
            int e = b + lane;
            if (e < end) {
                float t = as_[csrc[e]] + adn;
                t = t > 0.f ? t : NEG_SLOPE * t;
                sum += __expf(t - m);
            }
        }
#pragma unroll
        for (int o = 32; o; o >>= 1) sum += __shfl_xor(sum, o);
        float inv = 1.f / sum;
        for (int b = beg; b < end; b += 64) {
            int cnt = end - b; if (cnt > 64) cnt = 64;
            float p = 0.f; int s = 0;
            if (lane < cnt) {
                s = csrc[b + lane];
                float t = as_[s] + adn;
                t = t > 0.f ? t : NEG_SLOPE * t;
                p = __expf(t - m) * inv;
            }
            sps[wiw][lane] = make_float2(p, __int_as_float(s));
            int iters = (cnt + 7) >> 3;
#pragma unroll 8
            for (int j = 0; j < iters; j++) {
                float2 q = sps[wiw][j * 8 + sub];
                float a  = q.x;
                int   sj = __float_as_int(q.y);
                uint4 v  = xq[(size_t)sj * 8];
                acc[0] = fmaf(a, bf_lo(v.x), acc[0]); acc[1] = fmaf(a, bf_hi(v.x), acc[1]);
                acc[2] = fmaf(a, bf_lo(v.y), acc[2]); acc[3] = fmaf(a, bf_hi(v.y), acc[3]);
                acc[4] = fmaf(a, bf_lo(v.z), acc[4]); acc[5] = fmaf(a, bf_hi(v.z), acc[5]);
                acc[6] = fmaf(a, bf_lo(v.w), acc[6]); acc[7] = fmaf(a, bf_hi(v.w), acc[7]);
            }
        }
    }
#pragma unroll
    for (int o = 8; o <= 32; o <<= 1)
#pragma unroll
        for (int i = 0; i < 8; i++) acc[i] += __shfl_xor(acc[i], o);
    if (sub == 0) {
        float* op = out + (size_t)node * 64 + cl * 8;
        const float* bp = bias + cl * 8;
#pragma unroll
        for (int i = 0; i < 8; i++) op[i] = fmaxf(acc[i] + bp[i], 0.f);
    }
}

// ---------------- launcher ----------------

extern "C" void kernel_launch(void* const* d_in, const int* in_sizes, int n_in,
                              void* d_out, int out_size, void* d_ws, size_t ws_size,
                              hipStream_t stream) {
    const float* x        = (const float*)d_in[0];
    const int*   ei       = (const int*)d_in[1];   // int32 per harness convention
    const float* W1       = (const float*)d_in[2];
    const float* attS1    = (const float*)d_in[3];
    const float* attD1    = (const float*)d_in[4];
    const float* b1       = (const float*)d_in[5];
    const float* W2       = (const float*)d_in[6];
    const float* attS2    = (const float*)d_in[7];
    const float* attD2    = (const float*)d_in[8];
    const float* b2       = (const float*)d_in[9];
    float* out            = (float*)d_out;

    int N  = in_sizes[0] / 128;
    int E  = in_sizes[1] / 2;
    int EE = E + N;                    // with self-loops
    int K  = (N + NB - 1) >> LOG_NB;   // buckets (98 for N=50000)

    char* w = (char*)d_ws;
    auto alloc = [&](size_t bytes) -> void* {
        void* p = (void*)w;
        w += (bytes + 255) & ~(size_t)255;
        return p;
    };
    int*   bcnt = (int*)alloc((size_t)(K + 1) * 4);
    int*   boff = (int*)alloc((size_t)(K + 1) * 4);
    int*   bcur = (int*)alloc((size_t)(K + 1) * 4);
    int*   off  = (int*)alloc((size_t)(N + 1) * 4);
    int*   csrc = (int*)alloc((size_t)EE * 4);
    unsigned short* xl1 = (unsigned short*)alloc((size_t)N * 128 * 2);  // bf16; aliases bkt, xl2
    float* sd1  = (float*)alloc((size_t)N * 2 * 4);
    float* dd1  = (float*)alloc((size_t)N * 2 * 4);
    float* h1   = (float*)alloc((size_t)N * 128 * 4);

    unsigned int* bkt = (unsigned int*)xl1;  // 6.6MB < 12.8MB; dead before gemm writes xl1
    unsigned short* xl2 = xl1;               // layer-2 xl (bf16), xl1 dead by then
    float* sd2 = sd1;
    float* dd2 = dd1;

    hipMemsetAsync(bcnt, 0, (size_t)(K + 1) * 4, stream);

    int G  = 256;
    int CH = (EE + G - 1) / G;
    sort_count_kernel<<<G, 256, 0, stream>>>(ei, E, EE, K, CH, bcnt);
    sort_scan_kernel<<<1, MAXK, 0, stream>>>(bcnt, boff, bcur, K, EE);
    sort_scatter_kernel<<<G, 256, 0, stream>>>(ei, E, EE, K, CH, bcur, bkt);
    sort_finalize_kernel<<<K, 256, 0, stream>>>(bkt, boff, off, csrc, N);

    // ---- layer 1: H=2, C=64 ----
    gemm_att_kernel<128, 2><<<(N + 63) / 64, 256, 0, stream>>>(x, W1, attS1, attD1, xl1, sd1, dd1, N);
    agg1_kernel<<<(N + 3) / 4, 256, 0, stream>>>(xl1, sd1, dd1, b1, off, csrc, h1, N);

    // ---- layer 2: H=1, C=64 ----
    gemm_att_kernel<64, 1><<<(N + 127) / 128, 256, 0, stream>>>(h1, W2, attS2, attD2, xl2, sd2, dd2, N);
    agg2_kernel<<<(N + 3) / 4, 256, 0, stream>>>(xl2, sd2, dd2, b2, off, csrc, out, N);
}

// Round 8
// 344.063 us; speedup vs baseline: 1.0966x; 1.0966x over previous
//
#include <hip/hip_runtime.h>
#include <cstdint>
#include <cstddef>

#define NEG_SLOPE 0.2f

// Edge packing relies on N <= 65536 (here N = 50000): edge = src | (dst<<16).
// Self-loops are NOT sorted: they are placed analytically (one per node).
#define NB 128        // nodes per bucket
#define LOG_NB 7
#define MAXK 512

__device__ inline unsigned short f2bf(float f) {          // RNE fp32->bf16
    unsigned int u = __float_as_uint(f);
    u += 0x7FFFu + ((u >> 16) & 1u);
    return (unsigned short)(u >> 16);
}
__device__ inline float bf_lo(unsigned int u) { return __uint_as_float(u << 16); }
__device__ inline float bf_hi(unsigned int u) { return __uint_as_float(u & 0xFFFF0000u); }

// ---------------- P1: per-block bucket histogram (real edges only) ----------------
__global__ __launch_bounds__(256) void sort_count_kernel(const int* __restrict__ ei, int E,
                                                         int K, int CH, int* __restrict__ bcnt) {
    __shared__ int hist[MAXK];
    int tid = threadIdx.x;
    for (int i = tid; i < K; i += 256) hist[i] = 0;
    __syncthreads();
    int lo = blockIdx.x * CH;
    int hi = lo + CH; if (hi > E) hi = E;
    for (int e = lo + tid; e < hi; e += 256)
        atomicAdd(&hist[ei[(size_t)E + e] >> LOG_NB], 1);
    __syncthreads();
    for (int i = tid; i < K; i += 256)
        if (hist[i]) atomicAdd(&bcnt[i], hist[i]);
}

// ---------------- P2: scan bucket counts ----------------
__global__ void sort_scan_kernel(const int* __restrict__ bcnt, int* __restrict__ boff,
                                 int* __restrict__ bcur, int K, int E) {
    __shared__ int buf[MAXK];
    int tid = threadIdx.x;   // 512 threads
    int v = (tid < K) ? bcnt[tid] : 0;
    buf[tid] = v;
    __syncthreads();
    for (int o = 1; o < MAXK; o <<= 1) {
        int t = (tid >= o) ? buf[tid - o] : 0;
        __syncthreads();
        buf[tid] += t;
        __syncthreads();
    }
    if (tid < K) {
        int ex = buf[tid] - v;
        boff[tid] = ex;
        bcur[tid] = ex;
    }
    if (tid == K) boff[K] = E;
}

// ---------------- P3: scatter packed real edges into buckets ----------------
__global__ __launch_bounds__(256) void sort_scatter_kernel(const int* __restrict__ ei, int E,
                                                           int K, int CH, int* __restrict__ bcur,
                                                           unsigned int* __restrict__ bkt) {
    __shared__ int hist[MAXK];
    __shared__ int base[MAXK];
    int tid = threadIdx.x;
    for (int i = tid; i < K; i += 256) hist[i] = 0;
    __syncthreads();
    int lo = blockIdx.x * CH;
    int hi = lo + CH; if (hi > E) hi = E;
    for (int e = lo + tid; e < hi; e += 256)
        atomicAdd(&hist[ei[(size_t)E + e] >> LOG_NB], 1);
    __syncthreads();
    for (int i = tid; i < K; i += 256) {
        int c = hist[i];
        base[i] = c ? atomicAdd(&bcur[i], c) : 0;
    }
    __syncthreads();
    for (int i = tid; i < K; i += 256) hist[i] = 0;
    __syncthreads();
    for (int e = lo + tid; e < hi; e += 256) {
        int s = ei[e];
        int d = ei[(size_t)E + e];
        int k = d >> LOG_NB;
        int r = atomicAdd(&hist[k], 1);
        bkt[(size_t)base[k] + r] = (unsigned int)s | ((unsigned int)d << 16);
    }
}

// ---------------- P4: per-bucket CSR finalize (adds one self-loop slot per node) ----------------
__global__ __launch_bounds__(256) void sort_finalize_kernel(const unsigned int* __restrict__ bkt,
                                                            const int* __restrict__ boff,
                                                            int* __restrict__ off,
                                                            int* __restrict__ csrc, int N) {
    __shared__ int nhist[NB];
    __shared__ int loff[NB + 1];
    int k = blockIdx.x;
    int tid = threadIdx.x;
    int node0 = k << LOG_NB;
    int nh = N - node0; if (nh > NB) nh = NB;
    int beg = boff[k], end = boff[k + 1];
    for (int i = tid; i < NB; i += 256) nhist[i] = 0;
    __syncthreads();
    for (int e = beg + tid; e < end; e += 256)
        atomicAdd(&nhist[(bkt[e] >> 16) - node0], 1);
    __syncthreads();
    if (tid == 0) {
        int run = beg + node0;   // each preceding node contributes +1 self slot
        for (int i = 0; i < nh; i++) { loff[i] = run; run += nhist[i] + 1; }
        loff[nh] = run;
    }
    __syncthreads();
    for (int i = tid; i < nh; i += 256) off[node0 + i] = loff[i];
    if (node0 + nh == N && tid == 0) off[N] = loff[nh];
    // self-loop first in each node's list; cursor starts after it
    for (int i = tid; i < nh; i += 256) {
        csrc[loff[i]] = node0 + i;
        nhist[i] = loff[i] + 1;
    }
    __syncthreads();
    for (int e = beg + tid; e < end; e += 256) {
        unsigned int p = bkt[e];
        int pos = atomicAdd(&nhist[(p >> 16) - node0], 1);
        csrc[pos] = (int)(p & 0xFFFFu);
    }
}

// ---- GEMM + fused att dots (r6 known-good): 16 rows/block, W staged in K-halves ----

template <int FOUT, int H>
__global__ __launch_bounds__(256) void gemm_att_kernel(const float* __restrict__ X,
                                                       const float* __restrict__ W,
                                                       const float* __restrict__ attS,
                                                       const float* __restrict__ attD,
                                                       unsigned short* __restrict__ Ybf,
                                                       float* __restrict__ as_,
                                                       float* __restrict__ ad_, int N) {
    __shared__ float sW[64 * FOUT];
    __shared__ float sX[16 * 128];
    int tid = threadIdx.x;
    size_t rowbase = (size_t)blockIdx.x * 16;
    const float* xp = X + rowbase * 128;
    for (int i = tid; i < 16 * 128; i += 256) sX[i] = xp[i];

    constexpr int RPT = (16 * FOUT) / 256;
    int col = tid % FOUT;
    int rg  = tid / FOUT;
    int r0  = rg * RPT;
    float acc[RPT];
#pragma unroll
    for (int i = 0; i < RPT; i++) acc[i] = 0.f;

    for (int k0 = 0; k0 < 128; k0 += 64) {
        __syncthreads();
        for (int i = tid; i < 64 * FOUT; i += 256) sW[i] = W[(size_t)k0 * FOUT + i];
        __syncthreads();
#pragma unroll 4
        for (int k = 0; k < 64; k++) {
            float wv = sW[k * FOUT + col];
#pragma unroll
            for (int i = 0; i < RPT; i++)
                acc[i] += sX[(r0 + i) * 128 + k0 + k] * wv;
        }
    }
    unsigned short* yp = Ybf + rowbase * FOUT;
#pragma unroll
    for (int i = 0; i < RPT; i++) yp[(size_t)(r0 + i) * FOUT + col] = f2bf(acc[i]);

    // fused att dots: attS/attD laid out [H][64] -> head*64 + (col&63) == col
    int lane = tid & 63;
    int head = col >> 6;             // uniform within a wave
    float asv = attS[col];
    float adv = attD[col];
#pragma unroll
    for (int i = 0; i < RPT; i++) {
        float ps = acc[i] * asv;
        float pd = acc[i] * adv;
#pragma unroll
        for (int o = 32; o; o >>= 1) { ps += __shfl_xor(ps, o); pd += __shfl_xor(pd, o); }
        if (lane == 0) {
            size_t row = rowbase + r0 + i;
            as_[row * H + head] = ps;
            ad_[row * H + head] = pd;
        }
    }
}

// ---------------- layer-1 softmax+aggregate: one wave per NODE, both heads ----------------
// lane = (sub = lane>>4 in [0,4), cl = lane&15). Row = 256B = 16 x uint4; cl covers 8 ch.
// deg<=64 fast path: gather loop fully unrolled to 16 branchless iterations
// (padded sps slots have p=0, s=0 -> harmless, L1-resident).

__global__ __launch_bounds__(256) void agg1_kernel(const unsigned short* __restrict__ xl,
                                                   const float* __restrict__ as_,
                                                   const float* __restrict__ ad_,
                                                   const float* __restrict__ bias,
                                                   const int* __restrict__ off,
                                                   const int* __restrict__ csrc,
                                                   float* __restrict__ out, int N) {
    __shared__ float4 sps[4][64];   // {p0, p1, as_int(src), -}
    int wiw  = threadIdx.x >> 6;
    int lane = threadIdx.x & 63;
    int node = blockIdx.x * 4 + wiw;
    if (node >= N) return;
    int beg = off[node], end = off[node + 1];
    int deg = end - beg;
    float2 adn = ((const float2*)ad_)[node];

    int cl  = lane & 15;
    int sub = lane >> 4;
    int hd1 = (cl >> 3) & 1;    // lanes 8-15 of each 16-group: head 1
    float acc[8];
#pragma unroll
    for (int i = 0; i < 8; i++) acc[i] = 0.f;
    const uint4* xq = (const uint4*)xl + cl;   // + src*16

    if (deg <= 64) {
        int s = 0;
        float t0 = -1e30f, t1 = -1e30f;
        if (lane < deg) {
            s = csrc[beg + lane];
            float2 asv = ((const float2*)as_)[s];
            t0 = asv.x + adn.x; t0 = t0 > 0.f ? t0 : NEG_SLOPE * t0;
            t1 = asv.y + adn.y; t1 = t1 > 0.f ? t1 : NEG_SLOPE * t1;
        }
        float m0 = t0, m1 = t1;
#pragma unroll
        for (int o = 32; o; o >>= 1) {
            m0 = fmaxf(m0, __shfl_xor(m0, o));
            m1 = fmaxf(m1, __shfl_xor(m1, o));
        }
        float e0 = (lane < deg) ? __expf(t0 - m0) : 0.f;
        float e1 = (lane < deg) ? __expf(t1 - m1) : 0.f;
        float s0 = e0, s1 = e1;
#pragma unroll
        for (int o = 32; o; o >>= 1) { s0 += __shfl_xor(s0, o); s1 += __shfl_xor(s1, o); }
        sps[wiw][lane] = make_float4(e0 / s0, e1 / s1, __int_as_float(s), 0.f);
#pragma unroll
        for (int j = 0; j < 16; j++) {
            float4 q = sps[wiw][j * 4 + sub];
            float a  = hd1 ? q.y : q.x;
            int   sj = __float_as_int(q.z);
            uint4 v  = xq[(size_t)sj * 16];
            acc[0] = fmaf(a, bf_lo(v.x), acc[0]); acc[1] = fmaf(a, bf_hi(v.x), acc[1]);
            acc[2] = fmaf(a, bf_lo(v.y), acc[2]); acc[3] = fmaf(a, bf_hi(v.y), acc[3]);
            acc[4] = fmaf(a, bf_lo(v.z), acc[4]); acc[5] = fmaf(a, bf_hi(v.z), acc[5]);
            acc[6] = fmaf(a, bf_lo(v.w), acc[6]); acc[7] = fmaf(a, bf_hi(v.w), acc[7]);
        }
    } else {
        // 3-pass fallback (deg > 64)
        float m0 = -1e30f, m1 = -1e30f;
        for (int b = beg; b < end; b += 64) {
            int e = b + lane;
            if (e < end) {
                int s = csrc[e];
                float2 asv = ((const float2*)as_)[s];
                float t0 = asv.x + adn.x; t0 = t0 > 0.f ? t0 : NEG_SLOPE * t0;
                float t1 = asv.y + adn.y; t1 = t1 > 0.f ? t1 : NEG_SLOPE * t1;
                m0 = fmaxf(m0, t0); m1 = fmaxf(m1, t1);
            }
        }
#pragma unroll
        for (int o = 32; o; o >>= 1) {
            m0 = fmaxf(m0, __shfl_xor(m0, o));
            m1 = fmaxf(m1, __shfl_xor(m1, o));
        }
        float s0 = 0.f, s1 = 0.f;
        for (int b = beg; b < end; b += 64) {
            int e = b + lane;
            if (e < end) {
                int s = csrc[e];
                float2 asv = ((const float2*)as_)[s];
                float t0 = asv.x + adn.x; t0 = t0 > 0.f ? t0 : NEG_SLOPE * t0;
                float t1 = asv.y + adn.y; t1 = t1 > 0.f ? t1 : NEG_SLOPE * t1;
                s0 += __expf(t0 - m0); s1 += __expf(t1 - m1);
            }
        }
#pragma unroll
        for (int o = 32; o; o >>= 1) { s0 += __shfl_xor(s0, o); s1 += __shfl_xor(s1, o); }
        float i0 = 1.f / s0, i1 = 1.f / s1;
        for (int b = beg; b < end; b += 64) {
            int cnt = end - b; if (cnt > 64) cnt = 64;
            float p0 = 0.f, p1 = 0.f; int s = 0;
            if (lane < cnt) {
                s = csrc[b + lane];
                float2 asv = ((const float2*)as_)[s];
                float t0 = asv.x + adn.x; t0 = t0 > 0.f ? t0 : NEG_SLOPE * t0;
                float t1 = asv.y + adn.y; t1 = t1 > 0.f ? t1 : NEG_SLOPE * t1;
                p0 = __expf(t0 - m0) * i0; p1 = __expf(t1 - m1) * i1;
            }
            sps[wiw][lane] = make_float4(p0, p1, __int_as_float(s), 0.f);
#pragma unroll
            for (int j = 0; j < 16; j++) {
                float4 q = sps[wiw][j * 4 + sub];
                float a  = hd1 ? q.y : q.x;
                int   sj = __float_as_int(q.z);
                uint4 v  = xq[(size_t)sj * 16];
                acc[0] = fmaf(a, bf_lo(v.x), acc[0]); acc[1] = fmaf(a, bf_hi(v.x), acc[1]);
                acc[2] = fmaf(a, bf_lo(v.y), acc[2]); acc[3] = fmaf(a, bf_hi(v.y), acc[3]);
                acc[4] = fmaf(a, bf_lo(v.z), acc[4]); acc[5] = fmaf(a, bf_hi(v.z), acc[5]);
                acc[6] = fmaf(a, bf_lo(v.w), acc[6]); acc[7] = fmaf(a, bf_hi(v.w), acc[7]);
            }
        }
    }
    // reduce over sub (lane bits 4,5)
#pragma unroll
    for (int o = 16; o <= 32; o <<= 1)
#pragma unroll
        for (int i = 0; i < 8; i++) acc[i] += __shfl_xor(acc[i], o);
    if (sub == 0) {
        float* op = out + (size_t)node * 128 + cl * 8;
        const float* bp = bias + cl * 8;
#pragma unroll
        for (int i = 0; i < 8; i++) op[i] = fmaxf(acc[i] + bp[i], 0.f);
    }
}

// ---------------- layer-2 softmax+aggregate: one wave per node, H=1 ----------------
// lane = (sub = lane>>3 in [0,8), cl = lane&7). Row = 128B = 8 x uint4; fixed 8 iters.

__global__ __launch_bounds__(256) void agg2_kernel(const unsigned short* __restrict__ xl,
                                                   const float* __restrict__ as_,
                                                   const float* __restrict__ ad_,
                                                   const float* __restrict__ bias,
                                                   const int* __restrict__ off,
                                                   const int* __restrict__ csrc,
                                                   float* __restrict__ out, int N) {
    __shared__ float2 sps[4][64];   // {p, as_int(src)}
    int wiw  = threadIdx.x >> 6;
    int lane = threadIdx.x & 63;
    int node = blockIdx.x * 4 + wiw;
    if (node >= N) return;
    int beg = off[node], end = off[node + 1];
    int deg = end - beg;
    float adn = ad_[node];

    int cl  = lane & 7;
    int sub = lane >> 3;
    float acc[8];
#pragma unroll
    for (int i = 0; i < 8; i++) acc[i] = 0.f;
    const uint4* xq = (const uint4*)xl + cl;   // + src*8

    if (deg <= 64) {
        int s = 0;
        float t = -1e30f;
        if (lane < deg) {
            s = csrc[beg + lane];
            t = as_[s] + adn;
            t = t > 0.f ? t : NEG_SLOPE * t;
        }
        float m = t;
#pragma unroll
        for (int o = 32; o; o >>= 1) m = fmaxf(m, __shfl_xor(m, o));
        float ev = (lane < deg) ? __expf(t - m) : 0.f;
        float sum = ev;
#pragma unroll
        for (int o = 32; o; o >>= 1) sum += __shfl_xor(sum, o);
        sps[wiw][lane] = make_float2(ev / sum, __int_as_float(s));
#pragma unroll
        for (int j = 0; j < 8; j++) {
            float2 q = sps[wiw][j * 8 + sub];
            float a  = q.x;
            int   sj = __float_as_int(q.y);
            uint4 v  = xq[(size_t)sj * 8];
            acc[0] = fmaf(a, bf_lo(v.x), acc[0]); acc[1] = fmaf(a, bf_hi(v.x), acc[1]);
            acc[2] = fmaf(a, bf_lo(v.y), acc[2]); acc[3] = fmaf(a, bf_hi(v.y), acc[3]);
            acc[4] = fmaf(a, bf_lo(v.z), acc[4]); acc[5] = fmaf(a, bf_hi(v.z), acc[5]);
            acc[6] = fmaf(a, bf_lo(v.w), acc[6]); acc[7] = fmaf(a, bf_hi(v.w), acc[7]);
        }
    } else {
        float m = -1e30f;
        for (int b = beg; b < end; b += 64) {
            int e = b + lane;
            if (e < end) {
                float t = as_[csrc[e]] + adn;
                t = t > 0.f ? t : NEG_SLOPE * t;
                m = fmaxf(m, t);
            }
        }
#pragma unroll
        for (int o = 32; o; o >>= 1) m = fmaxf(m, __shfl_xor(m, o));
        float sum = 0.f;
        for (int b = beg; b < end; b += 64) {
            int e = b + lane;
            if (e < end) {
                float t = as_[csrc[e]] + adn;
                t = t > 0.f ? t : NEG_SLOPE * t;
                sum += __expf(t - m);
            }
        }
#pragma unroll
        for (int o = 32; o; o >>= 1) sum += __shfl_xor(sum, o);
        float inv = 1.f / sum;
        for (int b = beg; b < end; b += 64) {
            int cnt = end - b; if (cnt > 64) cnt = 64;
            float p = 0.f; int s = 0;
            if (lane < cnt) {
                s = csrc[b + lane];
                float t = as_[s] + adn;
                t = t > 0.f ? t : NEG_SLOPE * t;
                p = __expf(t - m) * inv;
            }
            sps[wiw][lane] = make_float2(p, __int_as_float(s));
#pragma unroll
            for (int j = 0; j < 8; j++) {
                float2 q = sps[wiw][j * 8 + sub];
                float a  = q.x;
                int   sj = __float_as_int(q.y);
                uint4 v  = xq[(size_t)sj * 8];
                acc[0] = fmaf(a, bf_lo(v.x), acc[0]); acc[1] = fmaf(a, bf_hi(v.x), acc[1]);
                acc[2] = fmaf(a, bf_lo(v.y), acc[2]); acc[3] = fmaf(a, bf_hi(v.y), acc[3]);
                acc[4] = fmaf(a, bf_lo(v.z), acc[4]); acc[5] = fmaf(a, bf_hi(v.z), acc[5]);
                acc[6] = fmaf(a, bf_lo(v.w), acc[6]); acc[7] = fmaf(a, bf_hi(v.w), acc[7]);
            }
        }
    }
#pragma unroll
    for (int o = 8; o <= 32; o <<= 1)
#pragma unroll
        for (int i = 0; i < 8; i++) acc[i] += __shfl_xor(acc[i], o);
    if (sub == 0) {
        float* op = out + (size_t)node * 64 + cl * 8;
        const float* bp = bias + cl * 8;
#pragma unroll
        for (int i = 0; i < 8; i++) op[i] = fmaxf(acc[i] + bp[i], 0.f);
    }
}

// ---------------- launcher ----------------

extern "C" void kernel_launch(void* const* d_in, const int* in_sizes, int n_in,
                              void* d_out, int out_size, void* d_ws, size_t ws_size,
                              hipStream_t stream) {
    const float* x        = (const float*)d_in[0];
    const int*   ei       = (const int*)d_in[1];   // int32 per harness convention
    const float* W1       = (const float*)d_in[2];
    const float* attS1    = (const float*)d_in[3];
    const float* attD1    = (const float*)d_in[4];
    const float* b1       = (const float*)d_in[5];
    const float* W2       = (const float*)d_in[6];
    const float* attS2    = (const float*)d_in[7];
    const float* attD2    = (const float*)d_in[8];
    const float* b2       = (const float*)d_in[9];
    float* out            = (float*)d_out;

    int N  = in_sizes[0] / 128;
    int E  = in_sizes[1] / 2;
    int EE = E + N;                    // with self-loops
    int K  = (N + NB - 1) >> LOG_NB;   // buckets (391 for N=50000)

    char* w = (char*)d_ws;
    auto alloc = [&](size_t bytes) -> void* {
        void* p = (void*)w;
        w += (bytes + 255) & ~(size_t)255;
        return p;
    };
    int*   bcnt = (int*)alloc((size_t)(K + 1) * 4);
    int*   boff = (int*)alloc((size_t)(K + 1) * 4);
    int*   bcur = (int*)alloc((size_t)(K + 1) * 4);
    int*   off  = (int*)alloc((size_t)(N + 1) * 4);
    int*   csrc = (int*)alloc((size_t)EE * 4);
    unsigned short* xl1 = (unsigned short*)alloc((size_t)N * 128 * 2);  // bf16; aliases bkt, xl2
    float* sd1  = (float*)alloc((size_t)N * 2 * 4);
    float* dd1  = (float*)alloc((size_t)N * 2 * 4);
    float* h1   = (float*)alloc((size_t)N * 128 * 4);

    unsigned int* bkt = (unsigned int*)xl1;  // 6.4MB < 12.8MB; dead before gemm writes xl1
    unsigned short* xl2 = xl1;               // layer-2 xl (bf16), xl1 dead by then
    float* sd2 = sd1;
    float* dd2 = dd1;

    hipMemsetAsync(bcnt, 0, (size_t)(K + 1) * 4, stream);

    int G  = 256;
    int CH = (E + G - 1) / G;
    sort_count_kernel<<<G, 256, 0, stream>>>(ei, E, K, CH, bcnt);
    sort_scan_kernel<<<1, MAXK, 0, stream>>>(bcnt, boff, bcur, K, E);
    sort_scatter_kernel<<<G, 256, 0, stream>>>(ei, E, K, CH, bcur, bkt);
    sort_finalize_kernel<<<K, 256, 0, stream>>>(bkt, boff, off, csrc, N);

    // ---- layer 1: H=2, C=64 ----
    gemm_att_kernel<128, 2><<<(N + 15) / 16, 256, 0, stream>>>(x, W1, attS1, attD1, xl1, sd1, dd1, N);
    agg1_kernel<<<(N + 3) / 4, 256, 0, stream>>>(xl1, sd1, dd1, b1, off, csrc, h1, N);

    // ---- layer 2: H=1, C=64 ----
    gemm_att_kernel<64, 1><<<(N + 15) / 16, 256, 0, stream>>>(h1, W2, attS2, attD2, xl2, sd2, dd2, N);
    agg2_kernel<<<(N + 3) / 4, 256, 0, stream>>>(xl2, sd2, dd2, b2, off, csrc, out, N);
}

// Round 9
// 330.306 us; speedup vs baseline: 1.1423x; 1.0416x over previous
//
#include <hip/hip_runtime.h>
#include <cstdint>
#include <cstddef>

#define NEG_SLOPE 0.2f

// Edge packing relies on N <= 65536 (here N = 50000): edge = src | (dst<<16).
// Self-loops are NOT sorted: they are placed analytically (one per node).
#define NB 512        // nodes per bucket
#define LOG_NB 9
#define MAXK 512

__device__ inline unsigned short f2bf(float f) {          // RNE fp32->bf16
    unsigned int u = __float_as_uint(f);
    u += 0x7FFFu + ((u >> 16) & 1u);
    return (unsigned short)(u >> 16);
}
__device__ inline float bf_lo(unsigned int u) { return __uint_as_float(u << 16); }
__device__ inline float bf_hi(unsigned int u) { return __uint_as_float(u & 0xFFFF0000u); }

// ---------------- P1: per-block bucket histogram (real edges only) ----------------
__global__ __launch_bounds__(256) void sort_count_kernel(const int* __restrict__ ei, int E,
                                                         int K, int CH, int* __restrict__ bcnt) {
    __shared__ int hist[MAXK];
    int tid = threadIdx.x;
    for (int i = tid; i < K; i += 256) hist[i] = 0;
    __syncthreads();
    int lo = blockIdx.x * CH;
    int hi = lo + CH; if (hi > E) hi = E;
    for (int e = lo + tid; e < hi; e += 256)
        atomicAdd(&hist[ei[(size_t)E + e] >> LOG_NB], 1);
    __syncthreads();
    for (int i = tid; i < K; i += 256)
        if (hist[i]) atomicAdd(&bcnt[i], hist[i]);
}

// ---------------- P2: scan bucket counts ----------------
__global__ void sort_scan_kernel(const int* __restrict__ bcnt, int* __restrict__ boff,
                                 int* __restrict__ bcur, int K, int E) {
    __shared__ int buf[MAXK];
    int tid = threadIdx.x;   // 512 threads
    int v = (tid < K) ? bcnt[tid] : 0;
    buf[tid] = v;
    __syncthreads();
    for (int o = 1; o < MAXK; o <<= 1) {
        int t = (tid >= o) ? buf[tid - o] : 0;
        __syncthreads();
        buf[tid] += t;
        __syncthreads();
    }
    if (tid < K) {
        int ex = buf[tid] - v;
        boff[tid] = ex;
        bcur[tid] = ex;
    }
    if (tid == K) boff[K] = E;
}

// ---------------- P3: scatter packed real edges into buckets ----------------
__global__ __launch_bounds__(256) void sort_scatter_kernel(const int* __restrict__ ei, int E,
                                                           int K, int CH, int* __restrict__ bcur,
                                                           unsigned int* __restrict__ bkt) {
    __shared__ int hist[MAXK];
    __shared__ int base[MAXK];
    int tid = threadIdx.x;
    for (int i = tid; i < K; i += 256) hist[i] = 0;
    __syncthreads();
    int lo = blockIdx.x * CH;
    int hi = lo + CH; if (hi > E) hi = E;
    for (int e = lo + tid; e < hi; e += 256)
        atomicAdd(&hist[ei[(size_t)E + e] >> LOG_NB], 1);
    __syncthreads();
    for (int i = tid; i < K; i += 256) {
        int c = hist[i];
        base[i] = c ? atomicAdd(&bcur[i], c) : 0;
    }
    __syncthreads();
    for (int i = tid; i < K; i += 256) hist[i] = 0;
    __syncthreads();
    for (int e = lo + tid; e < hi; e += 256) {
        int s = ei[e];
        int d = ei[(size_t)E + e];
        int k = d >> LOG_NB;
        int r = atomicAdd(&hist[k], 1);
        bkt[(size_t)base[k] + r] = (unsigned int)s | ((unsigned int)d << 16);
    }
}

// ---------------- P4: per-bucket CSR finalize (parallel prefix; +1 self slot per node) ----------------
__global__ __launch_bounds__(256) void sort_finalize_kernel(const unsigned int* __restrict__ bkt,
                                                            const int* __restrict__ boff,
                                                            int* __restrict__ off,
                                                            int* __restrict__ csrc, int N) {
    __shared__ int nhist[NB];
    __shared__ int part[256];
    __shared__ int loff[NB];
    int k = blockIdx.x;
    int tid = threadIdx.x;
    int node0 = k << LOG_NB;
    int nh = N - node0; if (nh > NB) nh = NB;
    int beg = boff[k], end = boff[k + 1];
    for (int i = tid; i < NB; i += 256) nhist[i] = 0;
    __syncthreads();
    for (int e = beg + tid; e < end; e += 256)
        atomicAdd(&nhist[(bkt[e] >> 16) - node0], 1);
    __syncthreads();
    // sizes v[i] = nhist[i]+1 (self slot); 2 entries per thread + ladder scan
    int i0 = 2 * tid, i1 = 2 * tid + 1;
    int v0 = (i0 < nh) ? nhist[i0] + 1 : 0;
    int v1 = (i1 < nh) ? nhist[i1] + 1 : 0;
    part[tid] = v0 + v1;
    __syncthreads();
    for (int o = 1; o < 256; o <<= 1) {
        int t = (tid >= o) ? part[tid - o] : 0;
        __syncthreads();
        part[tid] += t;
        __syncthreads();
    }
    int gbase = beg + node0;   // node0 self slots precede this bucket
    int base = gbase + ((tid > 0) ? part[tid - 1] : 0);
    if (i0 < nh) loff[i0] = base;
    if (i1 < nh) loff[i1] = base + v0;
    __syncthreads();
    for (int i = tid; i < nh; i += 256) {
        off[node0 + i] = loff[i];
        csrc[loff[i]] = node0 + i;   // self-loop first in each node's list
        nhist[i] = loff[i] + 1;      // cursor starts after self slot
    }
    if (node0 + nh == N && tid == 0) off[N] = gbase + part[255];
    __syncthreads();
    for (int e = beg + tid; e < end; e += 256) {
        unsigned int p = bkt[e];
        int pos = atomicAdd(&nhist[(p >> 16) - node0], 1);
        csrc[pos] = (int)(p & 0xFFFFu);
    }
}

// ---- GEMM + fused att dots, register-tiled 8 rows x 4 cols per thread ----
// Tile: ROWS x FOUT (ROWS = 8192/FOUT). K staged in halves of 64; float4 staging.

template <int FOUT, int H>
__global__ __launch_bounds__(256) void gemm_att_kernel(const float* __restrict__ X,
                                                       const float* __restrict__ W,
                                                       const float* __restrict__ attS,
                                                       const float* __restrict__ attD,
                                                       unsigned short* __restrict__ Ybf,
                                                       float* __restrict__ as_,
                                                       float* __restrict__ ad_, int N) {
    constexpr int ROWS = 8192 / FOUT;   // 64 (F=128) or 128 (F=64)
    constexpr int CG   = FOUT / 4;
    __shared__ float sX[ROWS][68];      // +4 pad keeps rows 16B-aligned, breaks bank stride
    __shared__ float sW[64 * FOUT];
    int tid = threadIdx.x;
    int rowbase = blockIdx.x * ROWS;
    int cg = tid % CG;
    int rg = tid / CG;
    int r0 = rg * 8;

    float acc[8][4];
#pragma unroll
    for (int i = 0; i < 8; i++)
#pragma unroll
        for (int c = 0; c < 4; c++) acc[i][c] = 0.f;

    for (int k0 = 0; k0 < 128; k0 += 64) {
        __syncthreads();
        for (int idx = tid; idx < ROWS * 16; idx += 256) {
            int r = idx >> 4, q = idx & 15;
            int row = rowbase + r;
            float4 val = (row < N) ? *(const float4*)&X[(size_t)row * 128 + k0 + q * 4]
                                   : make_float4(0.f, 0.f, 0.f, 0.f);
            *(float4*)&sX[r][q * 4] = val;
        }
        for (int idx = tid; idx < 16 * FOUT; idx += 256)
            *(float4*)&sW[idx * 4] = *(const float4*)&W[(size_t)k0 * FOUT + idx * 4];
        __syncthreads();
        for (int k = 0; k < 64; k += 4) {
            float4 xr[8];
#pragma unroll
            for (int i = 0; i < 8; i++)
                xr[i] = *(const float4*)&sX[r0 + i][k];
#pragma unroll
            for (int kk = 0; kk < 4; kk++) {
                float4 wv = ((const float4*)(sW + (size_t)(k + kk) * FOUT))[cg];
#pragma unroll
                for (int i = 0; i < 8; i++) {
                    float xv = (&xr[i].x)[kk];
                    acc[i][0] = fmaf(xv, wv.x, acc[i][0]);
                    acc[i][1] = fmaf(xv, wv.y, acc[i][1]);
                    acc[i][2] = fmaf(xv, wv.z, acc[i][2]);
                    acc[i][3] = fmaf(xv, wv.w, acc[i][3]);
                }
            }
        }
    }

    // store bf16 Y
#pragma unroll
    for (int i = 0; i < 8; i++) {
        int row = rowbase + r0 + i;
        if (row < N) {
            ushort4 v;
            v.x = f2bf(acc[i][0]); v.y = f2bf(acc[i][1]);
            v.z = f2bf(acc[i][2]); v.w = f2bf(acc[i][3]);
            *(ushort4*)(Ybf + (size_t)row * FOUT + cg * 4) = v;
        }
    }

    // fused att dots: reduce each row's 64-channel dot across the head's 16 cg-threads
    float4 asv = ((const float4*)attS)[cg];
    float4 adv = ((const float4*)attD)[cg];
    int head = (H == 2) ? (cg >> 4) : 0;
#pragma unroll
    for (int i = 0; i < 8; i++) {
        float ps = acc[i][0] * asv.x + acc[i][1] * asv.y + acc[i][2] * asv.z + acc[i][3] * asv.w;
        float pd = acc[i][0] * adv.x + acc[i][1] * adv.y + acc[i][2] * adv.z + acc[i][3] * adv.w;
#pragma unroll
        for (int o = 1; o <= 8; o <<= 1) { ps += __shfl_xor(ps, o); pd += __shfl_xor(pd, o); }
        int row = rowbase + r0 + i;
        if ((tid & 15) == 0 && row < N) {
            as_[(size_t)row * H + head] = ps;
            ad_[(size_t)row * H + head] = pd;
        }
    }
}

// ---------------- layer-1 softmax+aggregate: one wave per NODE, both heads ----------------

__global__ __launch_bounds__(256) void agg1_kernel(const unsigned short* __restrict__ xl,
                                                   const float* __restrict__ as_,
                                                   const float* __restrict__ ad_,
                                                   const float* __restrict__ bias,
                                                   const int* __restrict__ off,
                                                   const int* __restrict__ csrc,
                                                   float* __restrict__ out, int N) {
    __shared__ float4 sps[4][64];   // {p0, p1, as_int(src), -}
    int wiw  = threadIdx.x >> 6;
    int lane = threadIdx.x & 63;
    int node = blockIdx.x * 4 + wiw;
    if (node >= N) return;
    int beg = off[node], end = off[node + 1];
    int deg = end - beg;
    float2 adn = ((const float2*)ad_)[node];

    int cl  = lane & 15;
    int sub = lane >> 4;
    int hd1 = (cl >> 3) & 1;    // lanes 8-15 of each 16-group: head 1
    float acc[8];
#pragma unroll
    for (int i = 0; i < 8; i++) acc[i] = 0.f;
    const uint4* xq = (const uint4*)xl + cl;   // + src*16

    if (deg <= 64) {
        int s = 0;
        float t0 = -1e30f, t1 = -1e30f;
        if (lane < deg) {
            s = csrc[beg + lane];
            float2 asv = ((const float2*)as_)[s];
            t0 = asv.x + adn.x; t0 = t0 > 0.f ? t0 : NEG_SLOPE * t0;
            t1 = asv.y + adn.y; t1 = t1 > 0.f ? t1 : NEG_SLOPE * t1;
        }
        float m0 = t0, m1 = t1;
#pragma unroll
        for (int o = 32; o; o >>= 1) {
            m0 = fmaxf(m0, __shfl_xor(m0, o));
            m1 = fmaxf(m1, __shfl_xor(m1, o));
        }
        float e0 = (lane < deg) ? __expf(t0 - m0) : 0.f;
        float e1 = (lane < deg) ? __expf(t1 - m1) : 0.f;
        float s0 = e0, s1 = e1;
#pragma unroll
        for (int o = 32; o; o >>= 1) { s0 += __shfl_xor(s0, o); s1 += __shfl_xor(s1, o); }
        sps[wiw][lane] = make_float4(e0 / s0, e1 / s1, __int_as_float(s), 0.f);
#pragma unroll
        for (int j = 0; j < 16; j++) {
            float4 q = sps[wiw][j * 4 + sub];
            float a  = hd1 ? q.y : q.x;
            int   sj = __float_as_int(q.z);
            uint4 v  = xq[(size_t)sj * 16];
            acc[0] = fmaf(a, bf_lo(v.x), acc[0]); acc[1] = fmaf(a, bf_hi(v.x), acc[1]);
            acc[2] = fmaf(a, bf_lo(v.y), acc[2]); acc[3] = fmaf(a, bf_hi(v.y), acc[3]);
            acc[4] = fmaf(a, bf_lo(v.z), acc[4]); acc[5] = fmaf(a, bf_hi(v.z), acc[5]);
            acc[6] = fmaf(a, bf_lo(v.w), acc[6]); acc[7] = fmaf(a, bf_hi(v.w), acc[7]);
        }
    } else {
        // 3-pass fallback (deg > 64)
        float m0 = -1e30f, m1 = -1e30f;
        for (int b = beg; b < end; b += 64) {
            int e = b + lane;
            if (e < end) {
                int s = csrc[e];
                float2 asv = ((const float2*)as_)[s];
                float t0 = asv.x + adn.x; t0 = t0 > 0.f ? t0 : NEG_SLOPE * t0;
                float t1 = asv.y + adn.y; t1 = t1 > 0.f ? t1 : NEG_SLOPE * t1;
                m0 = fmaxf(m0, t0); m1 = fmaxf(m1, t1);
            }
        }
#pragma unroll
        for (int o = 32; o; o >>= 1) {
            m0 = fmaxf(m0, __shfl_xor(m0, o));
            m1 = fmaxf(m1, __shfl_xor(m1, o));
        }
        float s0 = 0.f, s1 = 0.f;
        for (int b = beg; b < end; b += 64) {
            int e = b + lane;
            if (e < end) {
                int s = csrc[e];
                float2 asv = ((const float2*)as_)[s];
                float t0 = asv.x + adn.x; t0 = t0 > 0.f ? t0 : NEG_SLOPE * t0;
                float t1 = asv.y + adn.y; t1 = t1 > 0.f ? t1 : NEG_SLOPE * t1;
                s0 += __expf(t0 - m0); s1 += __expf(t1 - m1);
            }
        }
#pragma unroll
        for (int o = 32; o; o >>= 1) { s0 += __shfl_xor(s0, o); s1 += __shfl_xor(s1, o); }
        float i0 = 1.f / s0, i1 = 1.f / s1;
        for (int b = beg; b < end; b += 64) {
            int cnt = end - b; if (cnt > 64) cnt = 64;
            float p0 = 0.f, p1 = 0.f; int s = 0;
            if (lane < cnt) {
                s = csrc[b + lane];
                float2 asv = ((const float2*)as_)[s];
                float t0 = asv.x + adn.x; t0 = t0 > 0.f ? t0 : NEG_SLOPE * t0;
                float t1 = asv.y + adn.y; t1 = t1 > 0.f ? t1 : NEG_SLOPE * t1;
                p0 = __expf(t0 - m0) * i0; p1 = __expf(t1 - m1) * i1;
            }
            sps[wiw][lane] = make_float4(p0, p1, __int_as_float(s), 0.f);
#pragma unroll
            for (int j = 0; j < 16; j++) {
                float4 q = sps[wiw][j * 4 + sub];
                float a  = hd1 ? q.y : q.x;
                int   sj = __float_as_int(q.z);
                uint4 v  = xq[(size_t)sj * 16];
                acc[0] = fmaf(a, bf_lo(v.x), acc[0]); acc[1] = fmaf(a, bf_hi(v.x), acc[1]);
                acc[2] = fmaf(a, bf_lo(v.y), acc[2]); acc[3] = fmaf(a, bf_hi(v.y), acc[3]);
                acc[4] = fmaf(a, bf_lo(v.z), acc[4]); acc[5] = fmaf(a, bf_hi(v.z), acc[5]);
                acc[6] = fmaf(a, bf_lo(v.w), acc[6]); acc[7] = fmaf(a, bf_hi(v.w), acc[7]);
            }
        }
    }
    // reduce over sub (lane bits 4,5)
#pragma unroll
    for (int o = 16; o <= 32; o <<= 1)
#pragma unroll
        for (int i = 0; i < 8; i++) acc[i] += __shfl_xor(acc[i], o);
    if (sub == 0) {
        float* op = out + (size_t)node * 128 + cl * 8;
        const float* bp = bias + cl * 8;
#pragma unroll
        for (int i = 0; i < 8; i++) op[i] = fmaxf(acc[i] + bp[i], 0.f);
    }
}

// ---------------- layer-2 softmax+aggregate: one wave per node, H=1 ----------------

__global__ __launch_bounds__(256) void agg2_kernel(const unsigned short* __restrict__ xl,
                                                   const float* __restrict__ as_,
                                                   const float* __restrict__ ad_,
                                                   const float* __restrict__ bias,
                                                   const int* __restrict__ off,
                                                   const int* __restrict__ csrc,
                                                   float* __restrict__ out, int N) {
    __shared__ float2 sps[4][64];   // {p, as_int(src)}
    int wiw  = threadIdx.x >> 6;
    int lane = threadIdx.x & 63;
    int node = blockIdx.x * 4 + wiw;
    if (node >= N) return;
    int beg = off[node], end = off[node + 1];
    int deg = end - beg;
    float adn = ad_[node];

    int cl  = lane & 7;
    int sub = lane >> 3;
    float acc[8];
#pragma unroll
    for (int i = 0; i < 8; i++) acc[i] = 0.f;
    const uint4* xq = (const uint4*)xl + cl;   // + src*8

    if (deg <= 64) {
        int s = 0;
        float t = -1e30f;
        if (lane < deg) {
            s = csrc[beg + lane];
            t = as_[s] + adn;
            t = t > 0.f ? t : NEG_SLOPE * t;
        }
        float m = t;
#pragma unroll
        for (int o = 32; o; o >>= 1) m = fmaxf(m, __shfl_xor(m, o));
        float ev = (lane < deg) ? __expf(t - m) : 0.f;
        float sum = ev;
#pragma unroll
        for (int o = 32; o; o >>= 1) sum += __shfl_xor(sum, o);
        sps[wiw][lane] = make_float2(ev / sum, __int_as_float(s));
#pragma unroll
        for (int j = 0; j < 8; j++) {
            float2 q = sps[wiw][j * 8 + sub];
            float a  = q.x;
            int   sj = __float_as_int(q.y);
            uint4 v  = xq[(size_t)sj * 8];
            acc[0] = fmaf(a, bf_lo(v.x), acc[0]); acc[1] = fmaf(a, bf_hi(v.x), acc[1]);
            acc[2] = fmaf(a, bf_lo(v.y), acc[2]); acc[3] = fmaf(a, bf_hi(v.y), acc[3]);
            acc[4] = fmaf(a, bf_lo(v.z), acc[4]); acc[5] = fmaf(a, bf_hi(v.z), acc[5]);
            acc[6] = fmaf(a, bf_lo(v.w), acc[6]); acc[7] = fmaf(a, bf_hi(v.w), acc[7]);
        }
    } else {
        float m = -1e30f;
        for (int b = beg; b < end; b += 64) {
            int e = b + lane;
            if (e < end) {
                float t = as_[csrc[e]] + adn;
                t = t > 0.f ? t : NEG_SLOPE * t;
                m = fmaxf(m, t);
            }
        }
#pragma unroll
        for (int o = 32; o; o >>= 1) m = fmaxf(m, __shfl_xor(m, o));
        float sum = 0.f;
        for (int b = beg; b < end; b += 64) {
            int e = b + lane;
            if (e < end) {
                float t = as_[csrc[e]] + adn;
                t = t > 0.f ? t : NEG_SLOPE * t;
                sum += __expf(t - m);
            }
        }
#pragma unroll
        for (int o = 32; o; o >>= 1) sum += __shfl_xor(sum, o);
        float inv = 1.f / sum;
        for (int b = beg; b < end; b += 64) {
            int cnt = end - b; if (cnt > 64) cnt = 64;
            float p = 0.f; int s = 0;
            if (lane < cnt) {
                s = csrc[b + lane];
                float t = as_[s] + adn;
                t = t > 0.f ? t : NEG_SLOPE * t;
                p = __expf(t - m) * inv;
            }
            sps[wiw][lane] = make_float2(p, __int_as_float(s));
#pragma unroll
            for (int j = 0; j < 8; j++) {
                float2 q = sps[wiw][j * 8 + sub];
                float a  = q.x;
                int   sj = __float_as_int(q.y);
                uint4 v  = xq[(size_t)sj * 8];
                acc[0] = fmaf(a, bf_lo(v.x), acc[0]); acc[1] = fmaf(a, bf_hi(v.x), acc[1]);
                acc[2] = fmaf(a, bf_lo(v.y), acc[2]); acc[3] = fmaf(a, bf_hi(v.y), acc[3]);
                acc[4] = fmaf(a, bf_lo(v.z), acc[4]); acc[5] = fmaf(a, bf_hi(v.z), acc[5]);
                acc[6] = fmaf(a, bf_lo(v.w), acc[6]); acc[7] = fmaf(a, bf_hi(v.w), acc[7]);
            }
        }
    }
#pragma unroll
    for (int o = 8; o <= 32; o <<= 1)
#pragma unroll
        for (int i = 0; i < 8; i++) acc[i] += __shfl_xor(acc[i], o);
    if (sub == 0) {
        float* op = out + (size_t)node * 64 + cl * 8;
        const float* bp = bias + cl * 8;
#pragma unroll
        for (int i = 0; i < 8; i++) op[i] = fmaxf(acc[i] + bp[i], 0.f);
    }
}

// ---------------- launcher ----------------

extern "C" void kernel_launch(void* const* d_in, const int* in_sizes, int n_in,
                              void* d_out, int out_size, void* d_ws, size_t ws_size,
                              hipStream_t stream) {
    const float* x        = (const float*)d_in[0];
    const int*   ei       = (const int*)d_in[1];   // int32 per harness convention
    const float* W1       = (const float*)d_in[2];
    const float* attS1    = (const float*)d_in[3];
    const float* attD1    = (const float*)d_in[4];
    const float* b1       = (const float*)d_in[5];
    const float* W2       = (const float*)d_in[6];
    const float* attS2    = (const float*)d_in[7];
    const float* attD2    = (const float*)d_in[8];
    const float* b2       = (const float*)d_in[9];
    float* out            = (float*)d_out;

    int N  = in_sizes[0] / 128;
    int E  = in_sizes[1] / 2;
    int EE = E + N;                    // with self-loops
    int K  = (N + NB - 1) >> LOG_NB;   // buckets (98 for N=50000)

    char* w = (char*)d_ws;
    auto alloc = [&](size_t bytes) -> void* {
        void* p = (void*)w;
        w += (bytes + 255) & ~(size_t)255;
        return p;
    };
    int*   bcnt = (int*)alloc((size_t)(K + 1) * 4);
    int*   boff = (int*)alloc((size_t)(K + 1) * 4);
    int*   bcur = (int*)alloc((size_t)(K + 1) * 4);
    int*   off  = (int*)alloc((size_t)(N + 1) * 4);
    int*   csrc = (int*)alloc((size_t)EE * 4);
    unsigned short* xl1 = (unsigned short*)alloc((size_t)N * 128 * 2);  // bf16; aliases bkt, xl2
    float* sd1  = (float*)alloc((size_t)N * 2 * 4);
    float* dd1  = (float*)alloc((size_t)N * 2 * 4);
    float* h1   = (float*)alloc((size_t)N * 128 * 4);

    unsigned int* bkt = (unsigned int*)xl1;  // 6.4MB < 12.8MB; dead before gemm writes xl1
    unsigned short* xl2 = xl1;               // layer-2 xl (bf16), xl1 dead by then
    float* sd2 = sd1;
    float* dd2 = dd1;

    hipMemsetAsync(bcnt, 0, (size_t)(K + 1) * 4, stream);

    int G  = 256;
    int CH = (E + G - 1) / G;
    sort_count_kernel<<<G, 256, 0, stream>>>(ei, E, K, CH, bcnt);
    sort_scan_kernel<<<1, MAXK, 0, stream>>>(bcnt, boff, bcur, K, E);
    sort_scatter_kernel<<<G, 256, 0, stream>>>(ei, E, K, CH, bcur, bkt);
    sort_finalize_kernel<<<K, 256, 0, stream>>>(bkt, boff, off, csrc, N);

    // ---- layer 1: H=2, C=64 ----
    gemm_att_kernel<128, 2><<<(N + 63) / 64, 256, 0, stream>>>(x, W1, attS1, attD1, xl1, sd1, dd1, N);
    agg1_kernel<<<(N + 3) / 4, 256, 0, stream>>>(xl1, sd1, dd1, b1, off, csrc, h1, N);

    // ---- layer 2: H=1, C=64 ----
    gemm_att_kernel<64, 1><<<(N + 127) / 128, 256, 0, stream>>>(h1, W2, attS2, attD2, xl2, sd2, dd2, N);
    agg2_kernel<<<(N + 3) / 4, 256, 0, stream>>>(xl2, sd2, dd2, b2, off, csrc, out, N);
}